// Round 3
// baseline (120.387 us; speedup 1.0000x reference)
//
#include <hip/hip_runtime.h>

// Problem constants
#define BATCH 16384
#define ZDIM  256
#define NCLS  1000
#define NPAD  1024

typedef __bf16 bf16x8 __attribute__((ext_vector_type(8)));
typedef float  f32x4  __attribute__((ext_vector_type(4)));

// Workspace layout (bytes). xb/cb are stored PRE-SWIZZLED in MFMA fragment
// order: chunk((tile,kt,lane)) = ((tile*8 + kt)*64 + lane) * 16B, where the
// chunk holds src[tile*16 + (lane&15)][kt*32 + (lane>>4)*8 .. +8] as bf16.
// A fragment load in the GEMM is then one lane-linear global_load_dwordx4.
//   xb  : bf16[16384*256] swizzled  @ 0         (8,388,608 B)
//   cb  : bf16[1024*256]  swizzled  @ 8388608   (524,288 B)
//   xsq : float[BATCH]              @ 8912896
//   csq : float[NPAD]               @ 8978432
//   acc : float[1]                  @ 8982528
//   cnt : uint[1]                   @ 8982532
#define WS_XB   0
#define WS_CB   8388608
#define WS_XSQ  8912896
#define WS_CSQ  8978432
#define WS_ACC  8982528
#define WS_CNT  8982532

__device__ __forceinline__ unsigned short f2bf(float f) {
    union { float f; unsigned int u; } v; v.f = f;
    unsigned int u = v.u;
    unsigned int r = (u + 0x7fffu + ((u >> 16) & 1u)) >> 16;   // RNE
    return (unsigned short)r;
}

// Fused prep. Blocks [0,256): x -> swizzled xb + xsq (wave per 16-row tile).
// Blocks [256,272): centers -> swizzled cb (zero-padded to 1024) + csq.
__global__ void prep(const float* __restrict__ x,
                     const float* __restrict__ centers,
                     unsigned short* __restrict__ xb,
                     unsigned short* __restrict__ cb,
                     float* __restrict__ xsq,
                     float* __restrict__ csq,
                     float* __restrict__ acc,
                     unsigned int* __restrict__ cnt) {
    const int wid  = threadIdx.x >> 6;
    const int lane = threadIdx.x & 63;
    const int lr   = lane & 15;
    const int quad = lane >> 4;

    if (blockIdx.x == 0 && threadIdx.x == 0) { *acc = 0.0f; *cnt = 0u; }

    if (blockIdx.x < 256) {
        const int mt = blockIdx.x * 4 + wid;                 // 0..1023
        const float* src = x + (size_t)(mt * 16 + lr) * ZDIM + quad * 8;
        float s = 0.0f;
        #pragma unroll
        for (int kt = 0; kt < 8; ++kt) {
            const float4 a = *(const float4*)(src + kt * 32);
            const float4 b = *(const float4*)(src + kt * 32 + 4);
            s += a.x*a.x + a.y*a.y + a.z*a.z + a.w*a.w
               + b.x*b.x + b.y*b.y + b.z*b.z + b.w*b.w;
            unsigned short* dst = xb + ((size_t)(mt * 8 + kt) * 64 + lane) * 8;
            ushort4 lo, hi;
            lo.x = f2bf(a.x); lo.y = f2bf(a.y); lo.z = f2bf(a.z); lo.w = f2bf(a.w);
            hi.x = f2bf(b.x); hi.y = f2bf(b.y); hi.z = f2bf(b.z); hi.w = f2bf(b.w);
            *(ushort4*)dst       = lo;
            *(ushort4*)(dst + 4) = hi;
        }
        s += __shfl_xor(s, 16);
        s += __shfl_xor(s, 32);
        if (lane < 16) xsq[mt * 16 + lane] = s;
    } else {
        const int ct  = (blockIdx.x - 256) * 4 + wid;        // 0..63
        const int row = ct * 16 + lr;
        const bool ok = (row < NCLS);
        const float* src = centers + (size_t)row * ZDIM + quad * 8;
        float s = 0.0f;
        #pragma unroll
        for (int kt = 0; kt < 8; ++kt) {
            float4 a = {0,0,0,0}, b = {0,0,0,0};
            if (ok) {
                a = *(const float4*)(src + kt * 32);
                b = *(const float4*)(src + kt * 32 + 4);
            }
            s += a.x*a.x + a.y*a.y + a.z*a.z + a.w*a.w
               + b.x*b.x + b.y*b.y + b.z*b.z + b.w*b.w;
            unsigned short* dst = cb + ((size_t)(ct * 8 + kt) * 64 + lane) * 8;
            ushort4 lo, hi;
            lo.x = f2bf(a.x); lo.y = f2bf(a.y); lo.z = f2bf(a.z); lo.w = f2bf(a.w);
            hi.x = f2bf(b.x); hi.y = f2bf(b.y); hi.z = f2bf(b.z); hi.w = f2bf(b.w);
            *(ushort4*)dst       = lo;
            *(ushort4*)(dst + 4) = hi;
        }
        s += __shfl_xor(s, 16);
        s += __shfl_xor(s, 32);
        if (lane < 16) csq[ct * 16 + lane] = s;   // pad rows accumulated zeros
    }
}

// Fused GEMM + distance + mask + reduce + finalize.
// NO LDS staging, NO K-loop barriers: fragments load directly from the
// pre-swizzled global layout (each load = 1KB lane-linear dwordx4, L2/L3-hot).
// 128x128 per block as 2x2 waves of 64x64; 16x16x32 bf16 MFMA.
__global__ __launch_bounds__(256, 3) void gemm_loss(
        const unsigned short* __restrict__ xb,
        const unsigned short* __restrict__ cb,
        const float* __restrict__ xsq,
        const float* __restrict__ csq,
        const int* __restrict__ labels,
        float* __restrict__ acc,
        unsigned int* __restrict__ cnt,
        float* __restrict__ out) {
    __shared__ float xsq_s[128];
    __shared__ float csq_s[128];
    __shared__ int   lab_s[128];
    __shared__ float wsum[4];

    const int tid  = threadIdx.x;
    const int lane = tid & 63;
    const int wid  = tid >> 6;
    const int bm   = blockIdx.x >> 3;      // 0..127
    const int bn   = blockIdx.x & 7;       // 0..7
    const int m0   = bm * 128;
    const int n0   = bn * 128;

    if (tid < 128) {
        xsq_s[tid] = xsq[m0 + tid];
        lab_s[tid] = labels[m0 + tid];
    } else {
        const int t = tid - 128;
        csq_s[t] = csq[n0 + t];
    }

    const int wm = wid & 1;      // wave row (0/1) -> 64 rows
    const int wn = wid >> 1;     // wave col (0/1) -> 64 cols

    f32x4 acc_r[4][4];
    #pragma unroll
    for (int i = 0; i < 4; ++i)
        #pragma unroll
        for (int j = 0; j < 4; ++j) {
            f32x4 z = {0.0f, 0.0f, 0.0f, 0.0f};
            acc_r[i][j] = z;
        }

    const int mtb = bm * 8 + wm * 4;       // first of 4 A 16-row tiles
    const int ctb = bn * 8 + wn * 4;       // first of 4 B 16-col tiles
    const bf16x8* __restrict__ A = (const bf16x8*)xb;
    const bf16x8* __restrict__ B = (const bf16x8*)cb;

    #pragma unroll
    for (int kt = 0; kt < 8; ++kt) {
        bf16x8 af[4], bfr[4];
        #pragma unroll
        for (int i = 0; i < 4; ++i)
            af[i] = A[(size_t)((mtb + i) * 8 + kt) * 64 + lane];
        #pragma unroll
        for (int j = 0; j < 4; ++j)
            bfr[j] = B[(size_t)((ctb + j) * 8 + kt) * 64 + lane];
        #pragma unroll
        for (int i = 0; i < 4; ++i)
            #pragma unroll
            for (int j = 0; j < 4; ++j)
                acc_r[i][j] = __builtin_amdgcn_mfma_f32_16x16x32_bf16(
                    af[i], bfr[j], acc_r[i][j], 0, 0, 0);
    }

    __syncthreads();   // staging of xsq_s/csq_s/lab_s visible before epilogue

    // Epilogue: dist -> sqrt -> clamp -> mask (label & pad) -> sum
    // C/D layout (16x16): col = lane&15, row = (lane>>4)*4 + reg  [m89/m91]
    const int quad = lane >> 4;
    const int lr   = lane & 15;
    float sum = 0.0f;
    #pragma unroll
    for (int j = 0; j < 4; ++j) {
        const int col_l = wn * 64 + j * 16 + lr;
        const int col_g = n0 + col_l;
        const float cs = csq_s[col_l];
        const bool colok = (col_g < NCLS);
        #pragma unroll
        for (int i = 0; i < 4; ++i) {
            #pragma unroll
            for (int r = 0; r < 4; ++r) {
                const int row_l = wm * 64 + i * 16 + quad * 4 + r;
                float dist = xsq_s[row_l] + cs - 2.0f * acc_r[i][j][r];
                float d = sqrtf(fmaxf(dist, 0.0f));
                d = fminf(fmaxf(d, 1e-8f), 1e8f);
                if (colok && (lab_s[row_l] != col_g)) sum += d;
            }
        }
    }

    #pragma unroll
    for (int off = 32; off; off >>= 1) sum += __shfl_down(sum, off);
    if (lane == 0) wsum[wid] = sum;
    __syncthreads();
    if (tid == 0) {
        atomicAdd(acc, wsum[0] + wsum[1] + wsum[2] + wsum[3]);
        __threadfence();
        const unsigned int prev = atomicAdd(cnt, 1u);
        if (prev == (unsigned int)(gridDim.x - 1)) {
            const float total = atomicAdd(acc, 0.0f);   // ordered read of acc
            out[0] = total * (1.0f / (16384.0f * 999.0f));
        }
    }
}

extern "C" void kernel_launch(void* const* d_in, const int* in_sizes, int n_in,
                              void* d_out, int out_size, void* d_ws, size_t ws_size,
                              hipStream_t stream) {
    const float* x       = (const float*)d_in[0];
    const float* centers = (const float*)d_in[1];
    const int*   labels  = (const int*)d_in[2];
    float*       out     = (float*)d_out;

    char* ws = (char*)d_ws;
    unsigned short* xb  = (unsigned short*)(ws + WS_XB);
    unsigned short* cb  = (unsigned short*)(ws + WS_CB);
    float*          xsq = (float*)(ws + WS_XSQ);
    float*          csq = (float*)(ws + WS_CSQ);
    float*          acc = (float*)(ws + WS_ACC);
    unsigned int*   cnt = (unsigned int*)(ws + WS_CNT);

    prep<<<272, 256, 0, stream>>>(x, centers, xb, cb, xsq, csq, acc, cnt);
    gemm_loss<<<(BATCH / 128) * (NPAD / 128), 256, 0, stream>>>(
        xb, cb, xsq, csq, labels, acc, cnt, out);
}

// Round 4
// 100.387 us; speedup vs baseline: 1.1992x; 1.1992x over previous
//
#include <hip/hip_runtime.h>

// Problem constants
#define BATCH 16384
#define ZDIM  256
#define NCLS  1000
#define NPAD  1024

typedef __bf16 bf16x8 __attribute__((ext_vector_type(8)));
typedef float  f32x4  __attribute__((ext_vector_type(4)));

// Workspace layout (bytes). xb/cb are stored PRE-SWIZZLED in MFMA fragment
// order: chunk((tile,kt,lane)) = ((tile*8 + kt)*64 + lane) * 16B, where the
// chunk holds src[tile*16 + (lane&15)][kt*32 + (lane>>4)*8 .. +8] as bf16.
// A fragment load in the GEMM is then one lane-linear global_load_dwordx4.
//   xb   : bf16[16384*256] swizzled  @ 0         (8,388,608 B)
//   cb   : bf16[1024*256]  swizzled  @ 8388608   (524,288 B)
//   xsq  : float[BATCH]              @ 8912896
//   csq  : float[NPAD]               @ 8978432
//   part : float[1024]               @ 8982528   (per-block partial sums)
#define WS_XB   0
#define WS_CB   8388608
#define WS_XSQ  8912896
#define WS_CSQ  8978432
#define WS_PART 8982528

__device__ __forceinline__ unsigned short f2bf(float f) {
    union { float f; unsigned int u; } v; v.f = f;
    unsigned int u = v.u;
    unsigned int r = (u + 0x7fffu + ((u >> 16) & 1u)) >> 16;   // RNE
    return (unsigned short)r;
}

// Fused prep. Blocks [0,256): x -> swizzled xb + xsq (wave per 16-row tile).
// Blocks [256,272): centers -> swizzled cb (zero-padded to 1024) + csq.
__global__ void prep(const float* __restrict__ x,
                     const float* __restrict__ centers,
                     unsigned short* __restrict__ xb,
                     unsigned short* __restrict__ cb,
                     float* __restrict__ xsq,
                     float* __restrict__ csq) {
    const int wid  = threadIdx.x >> 6;
    const int lane = threadIdx.x & 63;
    const int lr   = lane & 15;
    const int quad = lane >> 4;

    if (blockIdx.x < 256) {
        const int mt = blockIdx.x * 4 + wid;                 // 0..1023
        const float* src = x + (size_t)(mt * 16 + lr) * ZDIM + quad * 8;
        float s = 0.0f;
        #pragma unroll
        for (int kt = 0; kt < 8; ++kt) {
            const float4 a = *(const float4*)(src + kt * 32);
            const float4 b = *(const float4*)(src + kt * 32 + 4);
            s += a.x*a.x + a.y*a.y + a.z*a.z + a.w*a.w
               + b.x*b.x + b.y*b.y + b.z*b.z + b.w*b.w;
            unsigned short* dst = xb + ((size_t)(mt * 8 + kt) * 64 + lane) * 8;
            ushort4 lo, hi;
            lo.x = f2bf(a.x); lo.y = f2bf(a.y); lo.z = f2bf(a.z); lo.w = f2bf(a.w);
            hi.x = f2bf(b.x); hi.y = f2bf(b.y); hi.z = f2bf(b.z); hi.w = f2bf(b.w);
            *(ushort4*)dst       = lo;
            *(ushort4*)(dst + 4) = hi;
        }
        s += __shfl_xor(s, 16);
        s += __shfl_xor(s, 32);
        if (lane < 16) xsq[mt * 16 + lane] = s;
    } else {
        const int ct  = (blockIdx.x - 256) * 4 + wid;        // 0..63
        const int row = ct * 16 + lr;
        const bool ok = (row < NCLS);
        const float* src = centers + (size_t)row * ZDIM + quad * 8;
        float s = 0.0f;
        #pragma unroll
        for (int kt = 0; kt < 8; ++kt) {
            float4 a = {0,0,0,0}, b = {0,0,0,0};
            if (ok) {
                a = *(const float4*)(src + kt * 32);
                b = *(const float4*)(src + kt * 32 + 4);
            }
            s += a.x*a.x + a.y*a.y + a.z*a.z + a.w*a.w
               + b.x*b.x + b.y*b.y + b.z*b.z + b.w*b.w;
            unsigned short* dst = cb + ((size_t)(ct * 8 + kt) * 64 + lane) * 8;
            ushort4 lo, hi;
            lo.x = f2bf(a.x); lo.y = f2bf(a.y); lo.z = f2bf(a.z); lo.w = f2bf(a.w);
            hi.x = f2bf(b.x); hi.y = f2bf(b.y); hi.z = f2bf(b.z); hi.w = f2bf(b.w);
            *(ushort4*)dst       = lo;
            *(ushort4*)(dst + 4) = hi;
        }
        s += __shfl_xor(s, 16);
        s += __shfl_xor(s, 32);
        if (lane < 16) csq[ct * 16 + lane] = s;   // pad rows accumulated zeros
    }
}

// Fused GEMM + distance + mask + block reduce. NO device-scope atomics, NO
// fences: partial sum goes out as ONE plain global store per block.
// (Round-3 lesson: 1024 same-line device-scope atomics + __threadfence L2
// writebacks serialized ~50us; kernel-boundary ordering is free.)
// NO LDS staging, NO K-loop barriers: fragments load directly from the
// pre-swizzled global layout (each load = 1KB lane-linear dwordx4, L2/L3-hot).
// 128x128 per block as 2x2 waves of 64x64; 16x16x32 bf16 MFMA.
__global__ __launch_bounds__(256, 3) void gemm_loss(
        const unsigned short* __restrict__ xb,
        const unsigned short* __restrict__ cb,
        const float* __restrict__ xsq,
        const float* __restrict__ csq,
        const int* __restrict__ labels,
        float* __restrict__ part) {
    __shared__ float xsq_s[128];
    __shared__ float csq_s[128];
    __shared__ int   lab_s[128];
    __shared__ float wsum[4];

    const int tid  = threadIdx.x;
    const int lane = tid & 63;
    const int wid  = tid >> 6;
    const int bm   = blockIdx.x >> 3;      // 0..127
    const int bn   = blockIdx.x & 7;       // 0..7
    const int m0   = bm * 128;
    const int n0   = bn * 128;

    if (tid < 128) {
        xsq_s[tid] = xsq[m0 + tid];
        lab_s[tid] = labels[m0 + tid];
    } else {
        const int t = tid - 128;
        csq_s[t] = csq[n0 + t];
    }

    const int wm = wid & 1;      // wave row (0/1) -> 64 rows
    const int wn = wid >> 1;     // wave col (0/1) -> 64 cols

    f32x4 acc_r[4][4];
    #pragma unroll
    for (int i = 0; i < 4; ++i)
        #pragma unroll
        for (int j = 0; j < 4; ++j) {
            f32x4 z = {0.0f, 0.0f, 0.0f, 0.0f};
            acc_r[i][j] = z;
        }

    const int mtb = bm * 8 + wm * 4;       // first of 4 A 16-row tiles
    const int ctb = bn * 8 + wn * 4;       // first of 4 B 16-col tiles
    const bf16x8* __restrict__ A = (const bf16x8*)xb;
    const bf16x8* __restrict__ B = (const bf16x8*)cb;

    #pragma unroll
    for (int kt = 0; kt < 8; ++kt) {
        bf16x8 af[4], bfr[4];
        #pragma unroll
        for (int i = 0; i < 4; ++i)
            af[i] = A[(size_t)((mtb + i) * 8 + kt) * 64 + lane];
        #pragma unroll
        for (int j = 0; j < 4; ++j)
            bfr[j] = B[(size_t)((ctb + j) * 8 + kt) * 64 + lane];
        #pragma unroll
        for (int i = 0; i < 4; ++i)
            #pragma unroll
            for (int j = 0; j < 4; ++j)
                acc_r[i][j] = __builtin_amdgcn_mfma_f32_16x16x32_bf16(
                    af[i], bfr[j], acc_r[i][j], 0, 0, 0);
    }

    __syncthreads();   // staging of xsq_s/csq_s/lab_s visible before epilogue

    // Epilogue: dist -> sqrt -> clamp -> mask (label & pad) -> sum
    // C/D layout (16x16): col = lane&15, row = (lane>>4)*4 + reg  [m89/m91]
    const int quad = lane >> 4;
    const int lr   = lane & 15;
    float sum = 0.0f;
    #pragma unroll
    for (int j = 0; j < 4; ++j) {
        const int col_l = wn * 64 + j * 16 + lr;
        const int col_g = n0 + col_l;
        const float cs = csq_s[col_l];
        const bool colok = (col_g < NCLS);
        #pragma unroll
        for (int i = 0; i < 4; ++i) {
            #pragma unroll
            for (int r = 0; r < 4; ++r) {
                const int row_l = wm * 64 + i * 16 + quad * 4 + r;
                float dist = xsq_s[row_l] + cs - 2.0f * acc_r[i][j][r];
                float d = sqrtf(fmaxf(dist, 0.0f));
                d = fminf(fmaxf(d, 1e-8f), 1e8f);
                if (colok && (lab_s[row_l] != col_g)) sum += d;
            }
        }
    }

    #pragma unroll
    for (int off = 32; off; off >>= 1) sum += __shfl_down(sum, off);
    if (lane == 0) wsum[wid] = sum;
    __syncthreads();
    if (tid == 0) part[blockIdx.x] = wsum[0] + wsum[1] + wsum[2] + wsum[3];
}

// Reduce 1024 partials -> loss. One block; no atomics anywhere.
__global__ void finalize(const float* __restrict__ part, float* __restrict__ out) {
    const int tid  = threadIdx.x;
    const int lane = tid & 63;
    const int wid  = tid >> 6;
    __shared__ float wsum[4];
    float s = part[tid] + part[tid + 256] + part[tid + 512] + part[tid + 768];
    #pragma unroll
    for (int off = 32; off; off >>= 1) s += __shfl_down(s, off);
    if (lane == 0) wsum[wid] = s;
    __syncthreads();
    if (tid == 0)
        out[0] = (wsum[0] + wsum[1] + wsum[2] + wsum[3]) * (1.0f / (16384.0f * 999.0f));
}

extern "C" void kernel_launch(void* const* d_in, const int* in_sizes, int n_in,
                              void* d_out, int out_size, void* d_ws, size_t ws_size,
                              hipStream_t stream) {
    const float* x       = (const float*)d_in[0];
    const float* centers = (const float*)d_in[1];
    const int*   labels  = (const int*)d_in[2];
    float*       out     = (float*)d_out;

    char* ws = (char*)d_ws;
    unsigned short* xb   = (unsigned short*)(ws + WS_XB);
    unsigned short* cb   = (unsigned short*)(ws + WS_CB);
    float*          xsq  = (float*)(ws + WS_XSQ);
    float*          csq  = (float*)(ws + WS_CSQ);
    float*          part = (float*)(ws + WS_PART);

    prep<<<272, 256, 0, stream>>>(x, centers, xb, cb, xsq, csq);
    gemm_loss<<<(BATCH / 128) * (NPAD / 128), 256, 0, stream>>>(
        xb, cb, xsq, csq, labels, part);
    finalize<<<1, 256, 0, stream>>>(part, out);
}

// Round 5
// 93.461 us; speedup vs baseline: 1.2881x; 1.0741x over previous
//
#include <hip/hip_runtime.h>

// Problem constants
#define BATCH 16384
#define ZDIM  256
#define NCLS  1000
#define NPAD  1024

typedef __bf16 bf16x8 __attribute__((ext_vector_type(8)));
typedef float  f32x4  __attribute__((ext_vector_type(4)));

// Workspace layout (bytes). xb/cb are stored PRE-SWIZZLED in MFMA fragment
// order: chunk((tile,kt,lane)) = ((tile*8 + kt)*64 + lane) * 16B, where the
// chunk holds src[tile*16 + (lane&15)][kt*32 + (lane>>4)*8 .. +8] as bf16.
// A fragment load in the GEMM is then one lane-linear global_load_dwordx4.
//   xb   : bf16[16384*256] swizzled  @ 0         (8,388,608 B)
//   cb   : bf16[1024*256]  swizzled  @ 8388608   (524,288 B)
//   xsq  : float[BATCH]              @ 8912896
//   csq  : float[NPAD]               @ 8978432
//   part : float[1024]               @ 8982528   (per-block partial sums)
#define WS_XB   0
#define WS_CB   8388608
#define WS_XSQ  8912896
#define WS_CSQ  8978432
#define WS_PART 8982528

__device__ __forceinline__ unsigned short f2bf(float f) {
    union { float f; unsigned int u; } v; v.f = f;
    unsigned int u = v.u;
    unsigned int r = (u + 0x7fffu + ((u >> 16) & 1u)) >> 16;   // RNE
    return (unsigned short)r;
}

// Fused prep. Blocks [0,256): x -> swizzled xb + xsq (wave per 16-row tile).
// Blocks [256,272): centers -> swizzled cb (zero-padded to 1024) + csq.
__global__ void prep(const float* __restrict__ x,
                     const float* __restrict__ centers,
                     unsigned short* __restrict__ xb,
                     unsigned short* __restrict__ cb,
                     float* __restrict__ xsq,
                     float* __restrict__ csq) {
    const int wid  = threadIdx.x >> 6;
    const int lane = threadIdx.x & 63;
    const int lr   = lane & 15;
    const int quad = lane >> 4;

    if (blockIdx.x < 256) {
        const int mt = blockIdx.x * 4 + wid;                 // 0..1023
        const float* src = x + (size_t)(mt * 16 + lr) * ZDIM + quad * 8;
        float s = 0.0f;
        #pragma unroll
        for (int kt = 0; kt < 8; ++kt) {
            const float4 a = *(const float4*)(src + kt * 32);
            const float4 b = *(const float4*)(src + kt * 32 + 4);
            s += a.x*a.x + a.y*a.y + a.z*a.z + a.w*a.w
               + b.x*b.x + b.y*b.y + b.z*b.z + b.w*b.w;
            unsigned short* dst = xb + ((size_t)(mt * 8 + kt) * 64 + lane) * 8;
            ushort4 lo, hi;
            lo.x = f2bf(a.x); lo.y = f2bf(a.y); lo.z = f2bf(a.z); lo.w = f2bf(a.w);
            hi.x = f2bf(b.x); hi.y = f2bf(b.y); hi.z = f2bf(b.z); hi.w = f2bf(b.w);
            *(ushort4*)dst       = lo;
            *(ushort4*)(dst + 4) = hi;
        }
        s += __shfl_xor(s, 16);
        s += __shfl_xor(s, 32);
        if (lane < 16) xsq[mt * 16 + lane] = s;
    } else {
        const int ct  = (blockIdx.x - 256) * 4 + wid;        // 0..63
        const int row = ct * 16 + lr;
        const bool ok = (row < NCLS);
        const float* src = centers + (size_t)row * ZDIM + quad * 8;
        float s = 0.0f;
        #pragma unroll
        for (int kt = 0; kt < 8; ++kt) {
            float4 a = {0,0,0,0}, b = {0,0,0,0};
            if (ok) {
                a = *(const float4*)(src + kt * 32);
                b = *(const float4*)(src + kt * 32 + 4);
            }
            s += a.x*a.x + a.y*a.y + a.z*a.z + a.w*a.w
               + b.x*b.x + b.y*b.y + b.z*b.z + b.w*b.w;
            unsigned short* dst = cb + ((size_t)(ct * 8 + kt) * 64 + lane) * 8;
            ushort4 lo, hi;
            lo.x = f2bf(a.x); lo.y = f2bf(a.y); lo.z = f2bf(a.z); lo.w = f2bf(a.w);
            hi.x = f2bf(b.x); hi.y = f2bf(b.y); hi.z = f2bf(b.z); hi.w = f2bf(b.w);
            *(ushort4*)dst       = lo;
            *(ushort4*)(dst + 4) = hi;
        }
        s += __shfl_xor(s, 16);
        s += __shfl_xor(s, 32);
        if (lane < 16) csq[ct * 16 + lane] = s;   // pad rows accumulated zeros
    }
}

// Fused GEMM + distance + mask + block reduce.
// XCD-AWARE MAPPING (round-5 change): bm = blockIdx % 128, bn = blockIdx/128.
// With round-robin blockIdx->XCD (%8), all 8 blocks sharing A-tile bm satisfy
// blockIdx === bm (mod 8) -> SAME XCD. Per-XCD L2 working set: 1MB xb slice
// (reused across all bn) + 512KB cb. Kills the 8x cross-XCD A duplication
// that pinned FETCH at 33.8MB / ~650GB/s miss-path in rounds 2-4.
// 128x128 per block as 2x2 waves of 64x64; 16x16x32 bf16 MFMA; no LDS
// staging, no K barriers, partial sum out via one plain store.
__global__ __launch_bounds__(256, 3) void gemm_loss(
        const unsigned short* __restrict__ xb,
        const unsigned short* __restrict__ cb,
        const float* __restrict__ xsq,
        const float* __restrict__ csq,
        const int* __restrict__ labels,
        float* __restrict__ part) {
    __shared__ float xsq_s[128];
    __shared__ float csq_s[128];
    __shared__ int   lab_s[128];
    __shared__ float wsum[4];

    const int tid  = threadIdx.x;
    const int lane = tid & 63;
    const int wid  = tid >> 6;
    const int bm   = blockIdx.x & 127;     // 0..127  (same bm -> same XCD)
    const int bn   = blockIdx.x >> 7;      // 0..7
    const int m0   = bm * 128;
    const int n0   = bn * 128;

    if (tid < 128) {
        xsq_s[tid] = xsq[m0 + tid];
        lab_s[tid] = labels[m0 + tid];
    } else {
        const int t = tid - 128;
        csq_s[t] = csq[n0 + t];
    }

    const int wm = wid & 1;      // wave row (0/1) -> 64 rows
    const int wn = wid >> 1;     // wave col (0/1) -> 64 cols

    f32x4 acc_r[4][4];
    #pragma unroll
    for (int i = 0; i < 4; ++i)
        #pragma unroll
        for (int j = 0; j < 4; ++j) {
            f32x4 z = {0.0f, 0.0f, 0.0f, 0.0f};
            acc_r[i][j] = z;
        }

    const int mtb = bm * 8 + wm * 4;       // first of 4 A 16-row tiles
    const int ctb = bn * 8 + wn * 4;       // first of 4 B 16-col tiles
    const bf16x8* __restrict__ A = (const bf16x8*)xb;
    const bf16x8* __restrict__ B = (const bf16x8*)cb;

    #pragma unroll
    for (int kt = 0; kt < 8; ++kt) {
        bf16x8 af[4], bfr[4];
        #pragma unroll
        for (int i = 0; i < 4; ++i)
            af[i] = A[(size_t)((mtb + i) * 8 + kt) * 64 + lane];
        #pragma unroll
        for (int j = 0; j < 4; ++j)
            bfr[j] = B[(size_t)((ctb + j) * 8 + kt) * 64 + lane];
        #pragma unroll
        for (int i = 0; i < 4; ++i)
            #pragma unroll
            for (int j = 0; j < 4; ++j)
                acc_r[i][j] = __builtin_amdgcn_mfma_f32_16x16x32_bf16(
                    af[i], bfr[j], acc_r[i][j], 0, 0, 0);
    }

    __syncthreads();   // staging of xsq_s/csq_s/lab_s visible before epilogue

    // Epilogue: dist -> sqrt -> clamp -> mask (label & pad) -> sum
    // C/D layout (16x16): col = lane&15, row = (lane>>4)*4 + reg  [m89/m91]
    const int quad = lane >> 4;
    const int lr   = lane & 15;
    float sum = 0.0f;
    #pragma unroll
    for (int j = 0; j < 4; ++j) {
        const int col_l = wn * 64 + j * 16 + lr;
        const int col_g = n0 + col_l;
        const float cs = csq_s[col_l];
        const bool colok = (col_g < NCLS);
        #pragma unroll
        for (int i = 0; i < 4; ++i) {
            #pragma unroll
            for (int r = 0; r < 4; ++r) {
                const int row_l = wm * 64 + i * 16 + quad * 4 + r;
                float dist = xsq_s[row_l] + cs - 2.0f * acc_r[i][j][r];
                float d = sqrtf(fmaxf(dist, 0.0f));
                d = fminf(fmaxf(d, 1e-8f), 1e8f);
                if (colok && (lab_s[row_l] != col_g)) sum += d;
            }
        }
    }

    #pragma unroll
    for (int off = 32; off; off >>= 1) sum += __shfl_down(sum, off);
    if (lane == 0) wsum[wid] = sum;
    __syncthreads();
    if (tid == 0) part[blockIdx.x] = wsum[0] + wsum[1] + wsum[2] + wsum[3];
}

// Reduce 1024 partials -> loss. One block; no atomics anywhere.
__global__ void finalize(const float* __restrict__ part, float* __restrict__ out) {
    const int tid  = threadIdx.x;
    const int lane = tid & 63;
    const int wid  = tid >> 6;
    __shared__ float wsum[4];
    float s = part[tid] + part[tid + 256] + part[tid + 512] + part[tid + 768];
    #pragma unroll
    for (int off = 32; off; off >>= 1) s += __shfl_down(s, off);
    if (lane == 0) wsum[wid] = s;
    __syncthreads();
    if (tid == 0)
        out[0] = (wsum[0] + wsum[1] + wsum[2] + wsum[3]) * (1.0f / (16384.0f * 999.0f));
}

extern "C" void kernel_launch(void* const* d_in, const int* in_sizes, int n_in,
                              void* d_out, int out_size, void* d_ws, size_t ws_size,
                              hipStream_t stream) {
    const float* x       = (const float*)d_in[0];
    const float* centers = (const float*)d_in[1];
    const int*   labels  = (const int*)d_in[2];
    float*       out     = (float*)d_out;

    char* ws = (char*)d_ws;
    unsigned short* xb   = (unsigned short*)(ws + WS_XB);
    unsigned short* cb   = (unsigned short*)(ws + WS_CB);
    float*          xsq  = (float*)(ws + WS_XSQ);
    float*          csq  = (float*)(ws + WS_CSQ);
    float*          part = (float*)(ws + WS_PART);

    prep<<<272, 256, 0, stream>>>(x, centers, xb, cb, xsq, csq);
    gemm_loss<<<(BATCH / 128) * (NPAD / 128), 256, 0, stream>>>(
        xb, cb, xsq, csq, labels, part);
    finalize<<<1, 256, 0, stream>>>(part, out);
}